// Round 1
// baseline (407.510 us; speedup 1.0000x reference)
//
#include <hip/hip_runtime.h>
#include <hip/hip_bf16.h>

// SpectralConv2d (FNO): B=8, C_IN=C_OUT=32, H=W=256, modes 32x32 (low kx) + 32x32 (high kx), ky 0..31.
// Pipeline: partial rFFT(w) -> partial FFT(h) -> per-mode complex channel mix -> iFFT(h) -> irFFT(w)+bias.
// All twiddles via 256-entry cos/sin table indexed by (k*n)&255. 1/(H*W) and Hermitian 2x folded into weights.

#define BD 256

// tw[t] = (cos(2*pi*t/256), sin(2*pi*t/256))
__global__ void k_init_tw(float2* __restrict__ tw) {
    int t = threadIdx.x;
    double th = 6.283185307179586476925286766559 * (double)t / 256.0;
    tw[t] = make_float2((float)cos(th), (float)sin(th));
}

// wpack[(m*32+ky)*1024 + i*32 + o] = (w?r,w?i)[i][o][m'][ky] * c_ky / 65536
// m 0..31 -> w1 (kx=m), m 32..63 -> w2 (kx=224+(m-32))
__global__ void k_pack_w(const float* __restrict__ w1r, const float* __restrict__ w1i,
                         const float* __restrict__ w2r, const float* __restrict__ w2i,
                         float2* __restrict__ wpack) {
    int idx = blockIdx.x * BD + threadIdx.x;        // 0 .. 64*32*32*32-1
    int o  = idx & 31;
    int i  = (idx >> 5) & 31;
    int ky = (idx >> 10) & 31;
    int m  = idx >> 15;                             // 0..63
    float scale = (ky == 0 ? 1.0f : 2.0f) * (1.0f / 65536.0f);
    int widx = ((i * 32 + o) * 32 + (m & 31)) * 32 + ky;  // [I][O][m'][ky]
    float wr, wi;
    if (m < 32) { wr = w1r[widx]; wi = w1i[widx]; }
    else        { wr = w2r[widx]; wi = w2i[widx]; }
    wpack[idx] = make_float2(wr * scale, wi * scale);
}

// A1: Y[row][ky] = sum_w x[row][w] * e^{-2pi i ky w/256}, ky=0..31.  row = (b*32+i)*256+h.
// 8 rows per block, 32 threads per row (one ky each).
__global__ void k_dft_w(const float* __restrict__ x, const float2* __restrict__ tw,
                        float2* __restrict__ Y) {
    __shared__ float  xs[8][256];
    __shared__ float2 tws[256];
    int t = threadIdx.x;
    tws[t] = tw[t];
    const float* xb = x + (long)blockIdx.x * (8 * 256);
    for (int j = t; j < 8 * 256; j += BD) xs[j >> 8][j & 255] = xb[j];
    __syncthreads();
    int r = t >> 5;        // 0..7
    int ky = t & 31;
    float yr = 0.f, ys = 0.f;
    for (int w = 0; w < 256; ++w) {
        float v = xs[r][w];
        float2 tv = tws[(ky * w) & 255];
        yr = fmaf(v, tv.x, yr);
        ys = fmaf(v, tv.y, ys);
    }
    long rg = (long)blockIdx.x * 8 + r;
    Y[rg * 32 + ky] = make_float2(yr, -ys);
}

// A2: Z[bi][m][ky] = sum_h Y[bi][h][ky] * e^{-2pi i kx h/256}, kx = m<32 ? m : m+192.
// One block per bi (=b*32+i). Thread: m = t&63, ky block of 8 by quarter.
__global__ void k_dft_h(const float2* __restrict__ Y, const float2* __restrict__ tw,
                        float2* __restrict__ Z) {
    __shared__ float2 Ys[128][32];
    __shared__ float2 tws[256];
    int t = threadIdx.x;
    tws[t] = tw[t];
    int bi = blockIdx.x;
    int m = t & 63, q = t >> 6, ky0 = q * 8;
    int kx = (m < 32) ? m : m + 192;
    const float2* Yb = Y + (long)bi * 8192;    // 256 h * 32 ky
    float zr[8], zi[8];
#pragma unroll
    for (int j = 0; j < 8; ++j) { zr[j] = 0.f; zi[j] = 0.f; }
    for (int hc = 0; hc < 2; ++hc) {
        __syncthreads();
        for (int j = t; j < 128 * 32; j += BD) Ys[j >> 5][j & 31] = Yb[hc * 4096 + j];
        __syncthreads();
        for (int hh = 0; hh < 128; ++hh) {
            int h = hc * 128 + hh;
            float2 tv = tws[(kx * h) & 255];
#pragma unroll
            for (int j = 0; j < 8; ++j) {
                float2 y = Ys[hh][ky0 + j];
                zr[j] = fmaf(y.x, tv.x, fmaf(y.y,  tv.y, zr[j]));   // Re(Y * e^{-i th})
                zi[j] = fmaf(y.y, tv.x, fmaf(-y.x, tv.y, zi[j]));
            }
        }
    }
    float2* Zb = Z + ((long)bi * 64 + m) * 32 + ky0;
#pragma unroll
    for (int j = 0; j < 8; ++j) Zb[j] = make_float2(zr[j], zi[j]);
}

// B: Zmix[b][o][m][ky] = sum_i Z[b][i][m][ky] * Wpack[m][ky][i][o]   (complex)
// One block per (m,ky). Thread t = b*32+o.
__global__ void k_mix(const float2* __restrict__ Z, const float2* __restrict__ wpack,
                      float2* __restrict__ Zmix) {
    __shared__ float2 Zs[256];    // [b*32+i]
    __shared__ float2 Ws[1024];   // [i*32+o]
    int t = threadIdx.x;
    int mk = blockIdx.x;          // m*32+ky
    Zs[t] = Z[(long)t * 2048 + mk];
    for (int j = t; j < 1024; j += BD) Ws[j] = wpack[(long)mk * 1024 + j];
    __syncthreads();
    int b = t >> 5, o = t & 31;
    float ar = 0.f, ai = 0.f;
#pragma unroll
    for (int i = 0; i < 32; ++i) {
        float2 z = Zs[b * 32 + i];
        float2 w = Ws[i * 32 + o];
        ar = fmaf(z.x, w.x, fmaf(-z.y, w.y, ar));
        ai = fmaf(z.x, w.y, fmaf(z.y,  w.x, ai));
    }
    Zmix[(long)t * 2048 + mk] = make_float2(ar, ai);
}

// C1: G[bo][h][ky] = sum_m Zmix[bo][m][ky] * e^{+2pi i kx h/256}
__global__ void k_idft_h(const float2* __restrict__ Zmix, const float2* __restrict__ tw,
                         float2* __restrict__ G) {
    __shared__ float2 Zs[64][32];
    __shared__ float2 tws[256];
    int t = threadIdx.x;
    tws[t] = tw[t];
    int bo = blockIdx.x;
    const float2* Zb = Zmix + (long)bo * 2048;
    for (int j = t; j < 2048; j += BD) Zs[j >> 5][j & 31] = Zb[j];
    __syncthreads();
    int h = t;
    float gr[32], gi[32];
#pragma unroll
    for (int k = 0; k < 32; ++k) { gr[k] = 0.f; gi[k] = 0.f; }
    for (int m = 0; m < 64; ++m) {
        int kx = (m < 32) ? m : m + 192;
        float2 tv = tws[(kx * h) & 255];
#pragma unroll
        for (int ky = 0; ky < 32; ++ky) {
            float2 z = Zs[m][ky];
            gr[ky] = fmaf(z.x, tv.x, fmaf(-z.y, tv.y, gr[ky]));   // Re(Z * e^{+i th})
            gi[ky] = fmaf(z.y, tv.x, fmaf(z.x,  tv.y, gi[ky]));
        }
    }
    float2* Gb = G + ((long)bo * 256 + h) * 32;
#pragma unroll
    for (int ky = 0; ky < 32; ++ky) Gb[ky] = make_float2(gr[ky], gi[ky]);
}

// C2: out[row][w] = bias[o] + sum_ky ( Gr[ky]*cos(2pi ky w/256) - Gi[ky]*sin(...) )
// (scale + 2x folded into weights; ky=0 uses only Re via sin(0)=0; no Nyquist term)
__global__ void k_idft_w(const float2* __restrict__ G, const float2* __restrict__ tw,
                         const float* __restrict__ bias, float* __restrict__ out) {
    __shared__ float2 Gs[32];
    __shared__ float2 tws[256];
    int t = threadIdx.x;
    long row = blockIdx.x;          // (b*32+o)*256 + h
    tws[t] = tw[t];
    if (t < 32) Gs[t] = G[row * 32 + t];
    __syncthreads();
    int o = ((int)row >> 8) & 31;
    float acc = bias[o];
#pragma unroll
    for (int ky = 0; ky < 32; ++ky) {
        float2 tv = tws[(ky * t) & 255];
        float2 g = Gs[ky];
        acc = fmaf(g.x, tv.x, fmaf(-g.y, tv.y, acc));
    }
    out[row * 256 + t] = acc;
}

extern "C" void kernel_launch(void* const* d_in, const int* in_sizes, int n_in,
                              void* d_out, int out_size, void* d_ws, size_t ws_size,
                              hipStream_t stream) {
    const float* x    = (const float*)d_in[0];
    const float* w1r  = (const float*)d_in[1];
    const float* w1i  = (const float*)d_in[2];
    const float* w2r  = (const float*)d_in[3];
    const float* w2i  = (const float*)d_in[4];
    const float* bias = (const float*)d_in[5];

    char* ws = (char*)d_ws;
    float2* tw    = (float2*)(ws);                          // 2 KB
    float2* wpack = (float2*)(ws + 4096);                   // 16 MB
    float2* Y     = (float2*)(ws + 4096 + (16l << 20));     // 16 MB  (reused as G)
    float2* Z     = (float2*)(ws + 4096 + (32l << 20));     // 4 MB
    float2* Zmix  = (float2*)(ws + 4096 + (36l << 20));     // 4 MB
    float2* G     = Y;                                      // alias: Y dead after k_dft_h
    float*  out   = (float*)d_out;

    k_init_tw<<<1, BD, 0, stream>>>(tw);
    k_pack_w <<<(64 * 32 * 32 * 32) / BD, BD, 0, stream>>>(w1r, w1i, w2r, w2i, wpack);
    k_dft_w  <<<(8 * 32 * 256) / 8, BD, 0, stream>>>(x, tw, Y);
    k_dft_h  <<<8 * 32, BD, 0, stream>>>(Y, tw, Z);
    k_mix    <<<64 * 32, BD, 0, stream>>>(Z, wpack, Zmix);
    k_idft_h <<<8 * 32, BD, 0, stream>>>(Zmix, tw, G);
    k_idft_w <<<8 * 32 * 256, BD, 0, stream>>>(G, tw, bias, out);
}

// Round 3
// 253.236 us; speedup vs baseline: 1.6092x; 1.6092x over previous
//
#include <hip/hip_runtime.h>
#include <hip/hip_bf16.h>

// SpectralConv2d (FNO): B=8, C_IN=C_OUT=32, H=W=256, modes 32x32 (low kx) + 32x32 (high kx), ky 0..31.
// Pipeline: rFFT(w) as bf16-MFMA GEMM -> FFT(h) fp32 w/ rotation-recurrence twiddles -> complex mix
//           -> iFFT(h) fp32 recurrence (writes bf16) -> irFFT(w)+bias as bf16-MFMA GEMM.

#define BD 256

typedef __attribute__((ext_vector_type(8))) short bf16x8;
typedef __attribute__((ext_vector_type(4))) float f32x4;

__device__ inline unsigned short f2bf(float f) {
    union { float f; unsigned u; } v; v.f = f;
    unsigned r = v.u + 0x7FFF + ((v.u >> 16) & 1);   // RNE
    return (unsigned short)(r >> 16);
}

// tw[t] = (cos(2*pi*t/256), sin(2*pi*t/256))
__global__ void k_init_tw(float2* __restrict__ tw) {
    int t = threadIdx.x;
    double th = 6.283185307179586476925286766559 * (double)t / 256.0;
    tw[t] = make_float2((float)cos(th), (float)sin(th));
}

// BmA[n][w] (n=2ky+c, w=0..255): c=0 -> cos(2pi ky w/256), c=1 -> -sin   (A1 B-matrix, [64][256])
// BmC[w][k] (k=2ky+c):           c=0 -> cos(2pi ky w/256), c=1 -> -sin   (C2 B-matrix, [256][64])
__global__ void k_init_bmat(unsigned short* __restrict__ BmA, unsigned short* __restrict__ BmC) {
    int idx = blockIdx.x * BD + threadIdx.x;   // 0..32767
    if (idx < 16384) {
        int w = idx & 255, n = idx >> 8;
        int ky = n >> 1, c = n & 1;
        double th = 6.283185307179586476925286766559 * (double)((ky * w) & 255) / 256.0;
        BmA[idx] = f2bf(c ? (float)(-sin(th)) : (float)cos(th));
    } else {
        int j = idx - 16384;
        int k = j & 63, w = j >> 6;
        int ky = k >> 1, c = k & 1;
        double th = 6.283185307179586476925286766559 * (double)((ky * w) & 255) / 256.0;
        BmC[j] = f2bf(c ? (float)(-sin(th)) : (float)cos(th));
    }
}

// wpack[(m*32+ky)*1024 + i*32 + o] = w[i][o][m'][ky] * c_ky / 65536  (complex)
__global__ void k_pack_w(const float* __restrict__ w1r, const float* __restrict__ w1i,
                         const float* __restrict__ w2r, const float* __restrict__ w2i,
                         float2* __restrict__ wpack) {
    int idx = blockIdx.x * BD + threadIdx.x;
    int o  = idx & 31;
    int i  = (idx >> 5) & 31;
    int ky = (idx >> 10) & 31;
    int m  = idx >> 15;
    float scale = (ky == 0 ? 1.0f : 2.0f) * (1.0f / 65536.0f);
    int widx = ((i * 32 + o) * 32 + (m & 31)) * 32 + ky;
    float wr, wi;
    if (m < 32) { wr = w1r[widx]; wi = w1i[widx]; }
    else        { wr = w2r[widx]; wi = w2i[widx]; }
    wpack[idx] = make_float2(wr * scale, wi * scale);
}

// A1 (MFMA): Y[row][n] = sum_w x[row][w] * BmA[n][w].  M-tile=32 rows, N=64, K=256.
__global__ void k_dft_w_mfma(const float* __restrict__ x, const unsigned short* __restrict__ BmA,
                             float* __restrict__ Y) {
    __shared__ unsigned short As[32 * 264];   // 32 rows x 256 bf16, k-stride 264
    __shared__ unsigned short Bs[64 * 264];   // 64 n    x 256 bf16
    int t = threadIdx.x;
    {   // stage B (constant twiddle matrix): 64 shorts per row = 8 uint4
        int n = t >> 2, c0 = (t & 3) * 64;
        const uint4* src = (const uint4*)(BmA + n * 256 + c0);
        unsigned short* dst = &Bs[n * 264 + c0];
#pragma unroll
        for (int j = 0; j < 8; ++j) *(uint4*)(dst + j * 8) = src[j];
    }
    {   // stage A: fp32 x -> bf16
        int r = t >> 3, c0 = (t & 7) * 32;
        const float4* src = (const float4*)(x + ((long)blockIdx.x * 32 + r) * 256 + c0);
        unsigned short* dst = &As[r * 264 + c0];
#pragma unroll
        for (int j = 0; j < 8; ++j) {
            float4 v = src[j];
            ushort4 b;
            b.x = f2bf(v.x); b.y = f2bf(v.y); b.z = f2bf(v.z); b.w = f2bf(v.w);
            *(ushort4*)(dst + j * 4) = b;
        }
    }
    __syncthreads();
    int wv = t >> 6, lane = t & 63;
    int m = lane & 15, quad = lane >> 4;
    int rows16 = (wv >> 1) * 16;
    int ntb = (wv & 1) * 2;
    f32x4 acc[2] = {};
#pragma unroll
    for (int kk = 0; kk < 8; ++kk) {
        bf16x8 af = *(const bf16x8*)&As[(rows16 + m) * 264 + kk * 32 + quad * 8];
#pragma unroll
        for (int j = 0; j < 2; ++j) {
            bf16x8 bf = *(const bf16x8*)&Bs[((ntb + j) * 16 + m) * 264 + kk * 32 + quad * 8];
            acc[j] = __builtin_amdgcn_mfma_f32_16x16x32_bf16(af, bf, acc[j], 0, 0, 0);
        }
    }
    long Mbase = (long)blockIdx.x * 32 + rows16;
#pragma unroll
    for (int j = 0; j < 2; ++j)
#pragma unroll
        for (int r = 0; r < 4; ++r)
            Y[(Mbase + quad * 4 + r) * 64 + (ntb + j) * 16 + m] = acc[j][r];
}

// A2: Z[bi][m][ky] = sum_h Y[bi][h][ky] * e^{-2pi i kx h/256}.  Twiddle via rotation recurrence.
__global__ void k_dft_h(const float2* __restrict__ Y, const float2* __restrict__ tw,
                        float2* __restrict__ Z) {
    __shared__ __align__(16) float2 Ys[128][32];
    int t = threadIdx.x;
    int bi = blockIdx.x;
    int m = t & 63, q = t >> 6, ky0 = q * 8;
    int kx = (m < 32) ? m : m + 192;
    float2 st = tw[kx];                 // per-thread step e^{i 2pi kx/256}
    float C = st.x, S = st.y;
    float cr = 1.f, ci = 0.f;           // (cos th_h, sin th_h)
    const float2* Yb = Y + (long)bi * 8192;
    float zr[8], zi[8];
#pragma unroll
    for (int j = 0; j < 8; ++j) { zr[j] = 0.f; zi[j] = 0.f; }
    for (int hc = 0; hc < 2; ++hc) {
        __syncthreads();
        for (int j = t; j < 128 * 32; j += BD) Ys[j >> 5][j & 31] = Yb[hc * 4096 + j];
        __syncthreads();
        for (int hh = 0; hh < 128; ++hh) {
#pragma unroll
            for (int jj = 0; jj < 4; ++jj) {
                float4 y2 = *(const float4*)&Ys[hh][ky0 + jj * 2];
                zr[jj*2]   = fmaf(y2.x, cr, fmaf(y2.y,  ci, zr[jj*2]));
                zi[jj*2]   = fmaf(y2.y, cr, fmaf(-y2.x, ci, zi[jj*2]));
                zr[jj*2+1] = fmaf(y2.z, cr, fmaf(y2.w,  ci, zr[jj*2+1]));
                zi[jj*2+1] = fmaf(y2.w, cr, fmaf(-y2.z, ci, zi[jj*2+1]));
            }
            float nc = fmaf(cr, C, -ci * S);
            ci = fmaf(ci, C, cr * S);
            cr = nc;
        }
    }
    float2* Zb = Z + ((long)bi * 64 + m) * 32 + ky0;
#pragma unroll
    for (int j = 0; j < 8; ++j) Zb[j] = make_float2(zr[j], zi[j]);
}

// B: Zmix[b][o][m][ky] = sum_i Z[b][i][m][ky] * Wpack[m][ky][i][o]
__global__ void k_mix(const float2* __restrict__ Z, const float2* __restrict__ wpack,
                      float2* __restrict__ Zmix) {
    __shared__ float2 Zs[256];
    __shared__ float2 Ws[1024];
    int t = threadIdx.x;
    int mk = blockIdx.x;
    Zs[t] = Z[(long)t * 2048 + mk];
    for (int j = t; j < 1024; j += BD) Ws[j] = wpack[(long)mk * 1024 + j];
    __syncthreads();
    int b = t >> 5, o = t & 31;
    float ar = 0.f, ai = 0.f;
#pragma unroll
    for (int i = 0; i < 32; ++i) {
        float2 z = Zs[b * 32 + i];
        float2 w = Ws[i * 32 + o];
        ar = fmaf(z.x, w.x, fmaf(-z.y, w.y, ar));
        ai = fmaf(z.x, w.y, fmaf(z.y,  w.x, ai));
    }
    Zmix[(long)t * 2048 + mk] = make_float2(ar, ai);
}

// C1: G[bo][h][2ky+c] (bf16) = sum_m Zmix[bo][m][ky] * e^{+2pi i kx h/256}.  Recurrence twiddles.
__global__ void k_idft_h(const float2* __restrict__ Zmix, const float2* __restrict__ tw,
                         unsigned short* __restrict__ Gb) {
    __shared__ __align__(16) float2 Zs[64][32];
    int t = threadIdx.x;
    int bo = blockIdx.x;
    const float2* Zb = Zmix + (long)bo * 2048;
    for (int j = t; j < 2048; j += BD) Zs[j >> 5][j & 31] = Zb[j];
    float2 st = tw[t];                  // step e^{i 2pi h/256}, h = t
    float C = st.x, S = st.y;
    __syncthreads();
    float gr[32], gi[32];
#pragma unroll
    for (int k = 0; k < 32; ++k) { gr[k] = 0.f; gi[k] = 0.f; }
    float cr = 1.f, ci = 0.f;
    for (int half = 0; half < 2; ++half) {
        if (half) { float2 s2 = tw[(224 * t) & 255]; cr = s2.x; ci = s2.y; }
        for (int mm = 0; mm < 32; ++mm) {
            int m = half * 32 + mm;
#pragma unroll
            for (int kk = 0; kk < 16; ++kk) {
                float4 z = *(const float4*)&Zs[m][kk * 2];
                gr[kk*2]   = fmaf(z.x, cr, fmaf(-z.y, ci, gr[kk*2]));
                gi[kk*2]   = fmaf(z.y, cr, fmaf( z.x, ci, gi[kk*2]));
                gr[kk*2+1] = fmaf(z.z, cr, fmaf(-z.w, ci, gr[kk*2+1]));
                gi[kk*2+1] = fmaf(z.w, cr, fmaf( z.z, ci, gi[kk*2+1]));
            }
            float nc = fmaf(cr, C, -ci * S);
            ci = fmaf(ci, C, cr * S);
            cr = nc;
        }
    }
    unsigned* Gp = (unsigned*)(Gb + (((long)bo * 256 + t) * 64));
#pragma unroll
    for (int k = 0; k < 32; ++k)
        Gp[k] = (unsigned)f2bf(gr[k]) | ((unsigned)f2bf(gi[k]) << 16);
}

// C2 (MFMA): out[row][w] = bias + sum_k G[row][k] * BmC[w][k].  M-tile=64, N=256, K=64.
__global__ void k_idft_w_mfma(const unsigned short* __restrict__ Gb,
                              const unsigned short* __restrict__ BmC,
                              const float* __restrict__ bias, float* __restrict__ out) {
    __shared__ unsigned short As[64 * 72];    // 64 rows x 64 bf16, k-stride 72
    __shared__ unsigned short Bs[256 * 72];   // 256 w   x 64 bf16
    int t = threadIdx.x;
    {   // stage B: 64 shorts per row = 8 uint4  (BUGFIX: was j<4, left Bs[...][32..63] unwritten -> NaN)
        const uint4* src = (const uint4*)(BmC + t * 64);
        unsigned short* dst = &Bs[t * 72];
#pragma unroll
        for (int j = 0; j < 8; ++j) *(uint4*)(dst + j * 8) = src[j];
    }
    {   // stage A
        int r = t >> 2, c0 = (t & 3) * 16;
        const uint4* src = (const uint4*)(Gb + ((long)blockIdx.x * 64 + r) * 64 + c0);
        unsigned short* dst = &As[r * 72 + c0];
        *(uint4*)(dst) = src[0];
        *(uint4*)(dst + 8) = src[1];
    }
    __syncthreads();
    int wv = t >> 6, lane = t & 63;
    int m = lane & 15, quad = lane >> 4;
    f32x4 acc[16] = {};
    bf16x8 a0 = *(const bf16x8*)&As[(wv * 16 + m) * 72 + quad * 8];
    bf16x8 a1 = *(const bf16x8*)&As[(wv * 16 + m) * 72 + 32 + quad * 8];
#pragma unroll
    for (int nt = 0; nt < 16; ++nt) {
        bf16x8 b0 = *(const bf16x8*)&Bs[(nt * 16 + m) * 72 + quad * 8];
        bf16x8 b1 = *(const bf16x8*)&Bs[(nt * 16 + m) * 72 + 32 + quad * 8];
        acc[nt] = __builtin_amdgcn_mfma_f32_16x16x32_bf16(a0, b0, acc[nt], 0, 0, 0);
        acc[nt] = __builtin_amdgcn_mfma_f32_16x16x32_bf16(a1, b1, acc[nt], 0, 0, 0);
    }
    float bv = bias[(blockIdx.x >> 2) & 31];
    long rowbase = (long)blockIdx.x * 64 + wv * 16;
#pragma unroll
    for (int nt = 0; nt < 16; ++nt)
#pragma unroll
        for (int r = 0; r < 4; ++r)
            out[(rowbase + quad * 4 + r) * 256 + nt * 16 + m] = acc[nt][r] + bv;
}

extern "C" void kernel_launch(void* const* d_in, const int* in_sizes, int n_in,
                              void* d_out, int out_size, void* d_ws, size_t ws_size,
                              hipStream_t stream) {
    const float* x    = (const float*)d_in[0];
    const float* w1r  = (const float*)d_in[1];
    const float* w1i  = (const float*)d_in[2];
    const float* w2r  = (const float*)d_in[3];
    const float* w2i  = (const float*)d_in[4];
    const float* bias = (const float*)d_in[5];

    char* ws = (char*)d_ws;
    float2* tw             = (float2*)(ws);                                  // 2 KB (slot 4KB)
    float2* wpack          = (float2*)(ws + 4096);                           // 16 MB
    unsigned short* BmA    = (unsigned short*)(ws + 4096 + (16l << 20));     // 32 KB
    unsigned short* BmC    = BmA + 64 * 256;                                 // 32 KB
    float* Y               = (float*)(ws + 4096 + (16l << 20) + 65536);      // 16 MB
    float2* Z              = (float2*)((char*)Y + (16l << 20));              // 4 MB
    float2* Zmix           = (float2*)((char*)Z + (4l << 20));               // 4 MB
    unsigned short* Gb     = (unsigned short*)Y;   // alias: Y dead after k_dft_h
    float* out             = (float*)d_out;

    k_init_tw     <<<1, BD, 0, stream>>>(tw);
    k_init_bmat   <<<128, BD, 0, stream>>>(BmA, BmC);
    k_pack_w      <<<(64 * 32 * 32 * 32) / BD, BD, 0, stream>>>(w1r, w1i, w2r, w2i, wpack);
    k_dft_w_mfma  <<<2048, BD, 0, stream>>>(x, BmA, Y);
    k_dft_h       <<<256, BD, 0, stream>>>((const float2*)Y, tw, Z);
    k_mix         <<<2048, BD, 0, stream>>>(Z, wpack, Zmix);
    k_idft_h      <<<256, BD, 0, stream>>>(Zmix, tw, Gb);
    k_idft_w_mfma <<<1024, BD, 0, stream>>>(Gb, BmC, bias, out);
}

// Round 4
// 232.788 us; speedup vs baseline: 1.7506x; 1.0878x over previous
//
#include <hip/hip_runtime.h>
#include <hip/hip_bf16.h>

// SpectralConv2d (FNO): B=8, C_IN=C_OUT=32, H=W=256, modes 32x32 (low kx) + 32x32 (high kx), ky 0..31.
// Pipeline: rFFT(w) as bf16-MFMA GEMM -> FFT(h) fp32 w/ rotation-recurrence twiddles (ky-split x4)
//           -> complex mix -> iFFT(h) fp32 recurrence (ky-split x4, writes bf16)
//           -> irFFT(w)+bias as bf16-MFMA GEMM.

#define BD 256

typedef __attribute__((ext_vector_type(8))) short bf16x8;
typedef __attribute__((ext_vector_type(4))) float f32x4;

__device__ inline unsigned short f2bf(float f) {
    union { float f; unsigned u; } v; v.f = f;
    unsigned r = v.u + 0x7FFF + ((v.u >> 16) & 1);   // RNE
    return (unsigned short)(r >> 16);
}

// Merged setup: block 0 -> twiddle table; blocks 1..128 -> BmA/BmC; blocks 129.. -> wpack.
// tw[t] = (cos, sin)(2pi t/256)
// BmA[n][w] (n=2ky+c): c=0 -> cos(2pi ky w/256), c=1 -> -sin    [64][256]
// BmC[w][k] (k=2ky+c): c=0 -> cos, c=1 -> -sin                  [256][64]
// wpack[(m*32+ky)*1024 + i*32 + o] = w[i][o][m'][ky] * c_ky / 65536 (complex)
__global__ void k_setup(float2* __restrict__ tw,
                        unsigned short* __restrict__ BmA, unsigned short* __restrict__ BmC,
                        const float* __restrict__ w1r, const float* __restrict__ w1i,
                        const float* __restrict__ w2r, const float* __restrict__ w2i,
                        float2* __restrict__ wpack) {
    int b = blockIdx.x, t = threadIdx.x;
    if (b == 0) {
        double th = 6.283185307179586476925286766559 * (double)t / 256.0;
        tw[t] = make_float2((float)cos(th), (float)sin(th));
    } else if (b <= 128) {
        int idx = (b - 1) * BD + t;    // 0..32767
        if (idx < 16384) {
            int w = idx & 255, n = idx >> 8;
            int ky = n >> 1, c = n & 1;
            double th = 6.283185307179586476925286766559 * (double)((ky * w) & 255) / 256.0;
            BmA[idx] = f2bf(c ? (float)(-sin(th)) : (float)cos(th));
        } else {
            int j = idx - 16384;
            int k = j & 63, w = j >> 6;
            int ky = k >> 1, c = k & 1;
            double th = 6.283185307179586476925286766559 * (double)((ky * w) & 255) / 256.0;
            BmC[j] = f2bf(c ? (float)(-sin(th)) : (float)cos(th));
        }
    } else {
        int idx = (b - 129) * BD + t;  // 0..2097151
        int o  = idx & 31;
        int i  = (idx >> 5) & 31;
        int ky = (idx >> 10) & 31;
        int m  = idx >> 15;
        float scale = (ky == 0 ? 1.0f : 2.0f) * (1.0f / 65536.0f);
        int widx = ((i * 32 + o) * 32 + (m & 31)) * 32 + ky;
        float wr, wi;
        if (m < 32) { wr = w1r[widx]; wi = w1i[widx]; }
        else        { wr = w2r[widx]; wi = w2i[widx]; }
        wpack[idx] = make_float2(wr * scale, wi * scale);
    }
}

// A1 (MFMA): Y[row][n] = sum_w x[row][w] * BmA[n][w].  M-tile=32 rows, N=64, K=256.
__global__ void k_dft_w_mfma(const float* __restrict__ x, const unsigned short* __restrict__ BmA,
                             float* __restrict__ Y) {
    __shared__ unsigned short As[32 * 264];   // 32 rows x 256 bf16, k-stride 264
    __shared__ unsigned short Bs[64 * 264];   // 64 n    x 256 bf16
    int t = threadIdx.x;
    {   // stage B (constant twiddle matrix): 64 shorts per thread = 8 uint4
        int n = t >> 2, c0 = (t & 3) * 64;
        const uint4* src = (const uint4*)(BmA + n * 256 + c0);
        unsigned short* dst = &Bs[n * 264 + c0];
#pragma unroll
        for (int j = 0; j < 8; ++j) *(uint4*)(dst + j * 8) = src[j];
    }
    {   // stage A: fp32 x -> bf16
        int r = t >> 3, c0 = (t & 7) * 32;
        const float4* src = (const float4*)(x + ((long)blockIdx.x * 32 + r) * 256 + c0);
        unsigned short* dst = &As[r * 264 + c0];
#pragma unroll
        for (int j = 0; j < 8; ++j) {
            float4 v = src[j];
            ushort4 bq;
            bq.x = f2bf(v.x); bq.y = f2bf(v.y); bq.z = f2bf(v.z); bq.w = f2bf(v.w);
            *(ushort4*)(dst + j * 4) = bq;
        }
    }
    __syncthreads();
    int wv = t >> 6, lane = t & 63;
    int m = lane & 15, quad = lane >> 4;
    int rows16 = (wv >> 1) * 16;
    int ntb = (wv & 1) * 2;
    f32x4 acc[2] = {};
#pragma unroll
    for (int kk = 0; kk < 8; ++kk) {
        bf16x8 af = *(const bf16x8*)&As[(rows16 + m) * 264 + kk * 32 + quad * 8];
#pragma unroll
        for (int j = 0; j < 2; ++j) {
            bf16x8 bf = *(const bf16x8*)&Bs[((ntb + j) * 16 + m) * 264 + kk * 32 + quad * 8];
            acc[j] = __builtin_amdgcn_mfma_f32_16x16x32_bf16(af, bf, acc[j], 0, 0, 0);
        }
    }
    long Mbase = (long)blockIdx.x * 32 + rows16;
#pragma unroll
    for (int j = 0; j < 2; ++j)
#pragma unroll
        for (int r = 0; r < 4; ++r)
            Y[(Mbase + quad * 4 + r) * 64 + (ntb + j) * 16 + m] = acc[j][r];
}

// A2: Z[bi][m][ky] = sum_h Y[bi][h][ky] * e^{-2pi i kx h/256}.  Rotation-recurrence twiddles.
// Grid 1024: block = bi*4+q handles ky slice [q*8, q*8+8). Thread: m = t&63, sub = t>>6 (2 ky each).
__global__ void k_dft_h(const float2* __restrict__ Y, const float2* __restrict__ tw,
                        float2* __restrict__ Z) {
    __shared__ __align__(16) float2 Ys[256][8];   // [h][kk] 16 KB
    int t = threadIdx.x;
    int bi = blockIdx.x >> 2, ky0 = (blockIdx.x & 3) * 8;
    const float2* Yb = Y + (long)bi * 8192 + ky0;
    for (int j = t; j < 2048; j += BD) Ys[j >> 3][j & 7] = Yb[(j >> 3) * 32 + (j & 7)];
    int m = t & 63, sub = t >> 6;
    int kx = (m < 32) ? m : m + 192;
    float2 st = tw[kx];                 // step e^{i 2pi kx/256}
    float C = st.x, S = st.y;
    float cr = 1.f, ci = 0.f;
    float zr0 = 0.f, zi0 = 0.f, zr1 = 0.f, zi1 = 0.f;
    __syncthreads();
    for (int h = 0; h < 256; ++h) {
        float4 y = *(const float4*)&Ys[h][sub * 2];   // wave-broadcast
        zr0 = fmaf(y.x, cr, fmaf(y.y,  ci, zr0));
        zi0 = fmaf(y.y, cr, fmaf(-y.x, ci, zi0));
        zr1 = fmaf(y.z, cr, fmaf(y.w,  ci, zr1));
        zi1 = fmaf(y.w, cr, fmaf(-y.z, ci, zi1));
        float nc = fmaf(cr, C, -ci * S);
        ci = fmaf(ci, C, cr * S);
        cr = nc;
    }
    float2* Zb = Z + ((long)bi * 64 + m) * 32 + ky0 + sub * 2;
    Zb[0] = make_float2(zr0, zi0);
    Zb[1] = make_float2(zr1, zi1);
}

// B: Zmix[b][o][m][ky] = sum_i Z[b][i][m][ky] * Wpack[m][ky][i][o]
__global__ void k_mix(const float2* __restrict__ Z, const float2* __restrict__ wpack,
                      float2* __restrict__ Zmix) {
    __shared__ float2 Zs[256];
    __shared__ float2 Ws[1024];
    int t = threadIdx.x;
    int mk = blockIdx.x;
    Zs[t] = Z[(long)t * 2048 + mk];
    for (int j = t; j < 1024; j += BD) Ws[j] = wpack[(long)mk * 1024 + j];
    __syncthreads();
    int b = t >> 5, o = t & 31;
    float ar = 0.f, ai = 0.f;
#pragma unroll
    for (int i = 0; i < 32; ++i) {
        float2 z = Zs[b * 32 + i];
        float2 w = Ws[i * 32 + o];
        ar = fmaf(z.x, w.x, fmaf(-z.y, w.y, ar));
        ai = fmaf(z.x, w.y, fmaf(z.y,  w.x, ai));
    }
    Zmix[(long)t * 2048 + mk] = make_float2(ar, ai);
}

// C1: G[bo][h][2ky+c] (bf16) = sum_m Zmix[bo][m][ky] * e^{+2pi i kx h/256}.
// Grid 1024: block = bo*4+q handles ky slice [q*8, q*8+8). Thread t = h.
__global__ void k_idft_h(const float2* __restrict__ Zmix, const float2* __restrict__ tw,
                         unsigned short* __restrict__ Gb) {
    __shared__ __align__(16) float2 Zs[64][8];    // [m][kk] 4 KB
    int t = threadIdx.x;
    int bo = blockIdx.x >> 2, ky0 = (blockIdx.x & 3) * 8;
    const float2* Zb = Zmix + (long)bo * 2048 + ky0;
    for (int j = t; j < 512; j += BD) Zs[j >> 3][j & 7] = Zb[(j >> 3) * 32 + (j & 7)];
    float2 st = tw[t];                  // step e^{i 2pi h/256}, h = t
    float C = st.x, S = st.y;
    __syncthreads();
    float gr[8], gi[8];
#pragma unroll
    for (int k = 0; k < 8; ++k) { gr[k] = 0.f; gi[k] = 0.f; }
    float cr = 1.f, ci = 0.f;
    for (int half = 0; half < 2; ++half) {
        if (half) { float2 s2 = tw[(224 * t) & 255]; cr = s2.x; ci = s2.y; }
        for (int mm = 0; mm < 32; ++mm) {
            int m = half * 32 + mm;
#pragma unroll
            for (int kk = 0; kk < 4; ++kk) {
                float4 z = *(const float4*)&Zs[m][kk * 2];   // wave-broadcast
                gr[kk*2]   = fmaf(z.x, cr, fmaf(-z.y, ci, gr[kk*2]));
                gi[kk*2]   = fmaf(z.y, cr, fmaf( z.x, ci, gi[kk*2]));
                gr[kk*2+1] = fmaf(z.z, cr, fmaf(-z.w, ci, gr[kk*2+1]));
                gi[kk*2+1] = fmaf(z.w, cr, fmaf( z.z, ci, gi[kk*2+1]));
            }
            float nc = fmaf(cr, C, -ci * S);
            ci = fmaf(ci, C, cr * S);
            cr = nc;
        }
    }
    unsigned* Gp = (unsigned*)(Gb + (((long)bo * 256 + t) * 64 + ky0 * 2));
#pragma unroll
    for (int k = 0; k < 8; ++k)
        Gp[k] = (unsigned)f2bf(gr[k]) | ((unsigned)f2bf(gi[k]) << 16);
}

// C2 (MFMA): out[row][w] = bias + sum_k G[row][k] * BmC[w][k].  M-tile=64, N=256, K=64.
__global__ void k_idft_w_mfma(const unsigned short* __restrict__ Gb,
                              const unsigned short* __restrict__ BmC,
                              const float* __restrict__ bias, float* __restrict__ out) {
    __shared__ unsigned short As[64 * 72];    // 64 rows x 64 bf16, k-stride 72
    __shared__ unsigned short Bs[256 * 72];   // 256 w   x 64 bf16
    int t = threadIdx.x;
    {   // stage B: 64 shorts per row = 8 uint4
        const uint4* src = (const uint4*)(BmC + t * 64);
        unsigned short* dst = &Bs[t * 72];
#pragma unroll
        for (int j = 0; j < 8; ++j) *(uint4*)(dst + j * 8) = src[j];
    }
    {   // stage A
        int r = t >> 2, c0 = (t & 3) * 16;
        const uint4* src = (const uint4*)(Gb + ((long)blockIdx.x * 64 + r) * 64 + c0);
        unsigned short* dst = &As[r * 72 + c0];
        *(uint4*)(dst) = src[0];
        *(uint4*)(dst + 8) = src[1];
    }
    __syncthreads();
    int wv = t >> 6, lane = t & 63;
    int m = lane & 15, quad = lane >> 4;
    f32x4 acc[16] = {};
    bf16x8 a0 = *(const bf16x8*)&As[(wv * 16 + m) * 72 + quad * 8];
    bf16x8 a1 = *(const bf16x8*)&As[(wv * 16 + m) * 72 + 32 + quad * 8];
#pragma unroll
    for (int nt = 0; nt < 16; ++nt) {
        bf16x8 b0 = *(const bf16x8*)&Bs[(nt * 16 + m) * 72 + quad * 8];
        bf16x8 b1 = *(const bf16x8*)&Bs[(nt * 16 + m) * 72 + 32 + quad * 8];
        acc[nt] = __builtin_amdgcn_mfma_f32_16x16x32_bf16(a0, b0, acc[nt], 0, 0, 0);
        acc[nt] = __builtin_amdgcn_mfma_f32_16x16x32_bf16(a1, b1, acc[nt], 0, 0, 0);
    }
    float bv = bias[(blockIdx.x >> 2) & 31];
    long rowbase = (long)blockIdx.x * 64 + wv * 16;
#pragma unroll
    for (int nt = 0; nt < 16; ++nt)
#pragma unroll
        for (int r = 0; r < 4; ++r)
            out[(rowbase + quad * 4 + r) * 256 + nt * 16 + m] = acc[nt][r] + bv;
}

extern "C" void kernel_launch(void* const* d_in, const int* in_sizes, int n_in,
                              void* d_out, int out_size, void* d_ws, size_t ws_size,
                              hipStream_t stream) {
    const float* x    = (const float*)d_in[0];
    const float* w1r  = (const float*)d_in[1];
    const float* w1i  = (const float*)d_in[2];
    const float* w2r  = (const float*)d_in[3];
    const float* w2i  = (const float*)d_in[4];
    const float* bias = (const float*)d_in[5];

    char* ws = (char*)d_ws;
    float2* tw             = (float2*)(ws);                                  // 2 KB (slot 4KB)
    float2* wpack          = (float2*)(ws + 4096);                           // 16 MB
    unsigned short* BmA    = (unsigned short*)(ws + 4096 + (16l << 20));     // 32 KB
    unsigned short* BmC    = BmA + 64 * 256;                                 // 32 KB
    float* Y               = (float*)(ws + 4096 + (16l << 20) + 65536);      // 16 MB
    float2* Z              = (float2*)((char*)Y + (16l << 20));              // 4 MB
    float2* Zmix           = (float2*)((char*)Z + (4l << 20));               // 4 MB
    unsigned short* Gb     = (unsigned short*)Y;   // alias: Y dead after k_dft_h
    float* out             = (float*)d_out;

    k_setup       <<<1 + 128 + 8192, BD, 0, stream>>>(tw, BmA, BmC, w1r, w1i, w2r, w2i, wpack);
    k_dft_w_mfma  <<<2048, BD, 0, stream>>>(x, BmA, Y);
    k_dft_h       <<<1024, BD, 0, stream>>>((const float2*)Y, tw, Z);
    k_mix         <<<2048, BD, 0, stream>>>(Z, wpack, Zmix);
    k_idft_h      <<<1024, BD, 0, stream>>>(Zmix, tw, Gb);
    k_idft_w_mfma <<<1024, BD, 0, stream>>>(Gb, BmC, bias, out);
}